// Round 2
// baseline (418.645 us; speedup 1.0000x reference)
//
#include <hip/hip_runtime.h>
#include <cstdint>

#define B_ 16
#define H_ 224
#define W_ 224
#define C_ 32
#define TS 32      // output tile 32x32, 224 = 7*32
#define RG 47      // data rows/cols in halo region (32 + 7 top + 8 bottom)
#define SR 48      // SAT dim: exclusive 2D prefix needs +1 row & col

// ---- order-preserving float<->uint encoding for atomic min/max ----
__device__ __forceinline__ unsigned int enc_f(float f) {
    unsigned int u = __float_as_uint(f);
    return (u & 0x80000000u) ? ~u : (u | 0x80000000u);
}
__device__ __forceinline__ float dec_f(unsigned int u) {
    u = (u & 0x80000000u) ? (u & 0x7FFFFFFFu) : ~u;
    return __uint_as_float(u);
}

__global__ void init_ws(unsigned int* __restrict__ ws) {
    int t = threadIdx.x;
    if (t < 16) ws[t] = 0xFFFFFFFFu;
    else if (t < 32) ws[t] = 0u;
}

__global__ __launch_bounds__(256) void minmax_kernel(const float* __restrict__ x,
                                                     unsigned int* __restrict__ ws) {
    const int b = blockIdx.x;
    const int chunk = blockIdx.y;
    const int chunkElems = (H_ * W_ * C_) / 64;
    const float4* p = (const float4*)(x + (size_t)b * (H_ * W_ * C_) +
                                      (size_t)chunk * chunkElems);
    const int n4 = chunkElems / 4;
    float mn = 3.4e38f, mx = -3.4e38f;
    for (int i = threadIdx.x; i < n4; i += 256) {
        float4 v = p[i];
        mn = fminf(mn, fminf(fminf(v.x, v.y), fminf(v.z, v.w)));
        mx = fmaxf(mx, fmaxf(fmaxf(v.x, v.y), fmaxf(v.z, v.w)));
    }
#pragma unroll
    for (int off = 32; off > 0; off >>= 1) {
        mn = fminf(mn, __shfl_down(mn, off));
        mx = fmaxf(mx, __shfl_down(mx, off));
    }
    __shared__ float smn[4], smx[4];
    const int lane = threadIdx.x & 63, wv = threadIdx.x >> 6;
    if (lane == 0) { smn[wv] = mn; smx[wv] = mx; }
    __syncthreads();
    if (threadIdx.x == 0) {
        mn = fminf(fminf(smn[0], smn[1]), fminf(smn[2], smn[3]));
        mx = fmaxf(fmaxf(smx[0], smx[1]), fmaxf(smx[2], smx[3]));
        atomicMin(&ws[b], enc_f(mn));
        atomicMax(&ws[16 + b], enc_f(mx));
    }
}

// Box sum via 2D exclusive SAT corner reads. All 4 channels of a group live
// in one float4 -> every hot LDS op is a lane-consecutive b128 (conflict-free).
// IMPORTANT: the SAT is built on the SCALED values (x-mn)*inv, because TF
// SAME padding pads with zeros in the *scaled* domain — folding the scaling
// into the consume is wrong at image borders (round-1 failure, absmax 0.578).
#define LG(v) __log2f(fmaxf((v), 0.0f) + 1e-7f)

#define BOX(o, sc, bx) {                                                 \
        float4 q00 = SAT[hl + (o)][wl + (o)];                            \
        float4 q01 = SAT[hl + (o)][wl + (o) + (sc)];                     \
        float4 q10 = SAT[hl + (o) + (sc)][wl + (o)];                     \
        float4 q11 = SAT[hl + (o) + (sc)][wl + (o) + (sc)];              \
        bx.x = q11.x - q01.x - q10.x + q00.x;                            \
        bx.y = q11.y - q01.y - q10.y + q00.y;                            \
        bx.z = q11.z - q01.z - q10.z + q00.z;                            \
        bx.w = q11.w - q01.w - q10.w + q00.w; }

__global__ __launch_bounds__(512, 8) void lss_kernel(
    const float* __restrict__ x,
    const float* __restrict__ gamma, const float* __restrict__ beta,
    const float* __restrict__ mmean, const float* __restrict__ mvar,
    const unsigned int* __restrict__ ws,
    float* __restrict__ out)
{
    __shared__ float4 SAT[SR][SR];   // 36,864 B -> 4 blocks/CU

    const int bi = blockIdx.x;
    const int grp = bi >> 4, wi = bi & 15;
    const int s = (wi >> 3) & 1;           // channel half: ch s*16 .. s*16+15
    const int tile = grp * 8 + (wi & 7);   // splits of a tile land on same XCD
    const int b = tile / 49;
    const int t2 = tile - b * 49;
    const int th0 = (t2 / 7) * TS;
    const int tw0 = (t2 % 7) * TS;
    const int tid = threadIdx.x;
    const int lane = tid & 63, wv = tid >> 6;   // 8 waves

    const float mn = dec_f(ws[b]);
    const float mx = dec_f(ws[16 + b]);
    const float inv = 1.0f / (mx - mn + 1e-7f);

    const float* xb = x + (size_t)b * (H_ * W_ * C_);
    float* ob = out + (size_t)b * (H_ * W_ * C_);

    for (int cc = 0; cc < 4; ++cc) {
        const int ch0 = s * 16 + cc * 4;

        __syncthreads();   // protect SAT from previous iteration's consumers

        // ---- P0: load region row (scaled) + horizontal inclusive shuffle
        //          scan, write exclusive H-prefix (col j = sum of cols < j) ----
        for (int rr = wv; rr < RG; rr += 8) {
            const int gh = th0 - 7 + rr;
            const int gw = tw0 - 7 + lane;
            float4 v = make_float4(0.f, 0.f, 0.f, 0.f);
            if (lane < RG && gh >= 0 && gh < H_ && gw >= 0 && gw < W_) {
                const float4 t = *(const float4*)(xb + ((size_t)(gh * W_ + gw)) * C_ + ch0);
                v.x = (t.x - mn) * inv; v.y = (t.y - mn) * inv;
                v.z = (t.z - mn) * inv; v.w = (t.w - mn) * inv;
            }
#pragma unroll
            for (int off = 1; off < 64; off <<= 1) {
                float nx = __shfl_up(v.x, off);
                float ny = __shfl_up(v.y, off);
                float nz = __shfl_up(v.z, off);
                float nw = __shfl_up(v.w, off);
                if (lane >= off) { v.x += nx; v.y += ny; v.z += nz; v.w += nw; }
            }
            if (lane < RG) SAT[rr][lane + 1] = v;
            else if (lane == 63) SAT[rr][0] = make_float4(0.f, 0.f, 0.f, 0.f);
        }
        __syncthreads();

        // ---- P1: in-place exclusive vertical scan, one thread per SCALAR
        //          column (192 threads = 3 waves; consecutive tids hit
        //          consecutive banks -> 2-way aliasing per wave = free) ----
        if (tid < SR * 4) {
            float* col = (float*)SAT + tid;   // [48][192] scalar view
            float accv = 0.f;
#pragma unroll
            for (int r = 0; r < SR; ++r) {
                const float t = (r < RG) ? col[r * (SR * 4)] : 0.f;
                col[r * (SR * 4)] = accv;
                accv += t;
            }
        }
        __syncthreads();

        // ---- P2: consume all 4 scales from SAT corners, BN, store ----
        const float4 g4  = *(const float4*)(gamma + ch0);
        const float4 be4 = *(const float4*)(beta  + ch0);
        const float4 mm4 = *(const float4*)(mmean + ch0);
        const float4 mv4 = *(const float4*)(mvar  + ch0);
        const float bs0 = g4.x * rsqrtf(mv4.x + 1e-3f);
        const float bs1 = g4.y * rsqrtf(mv4.y + 1e-3f);
        const float bs2 = g4.z * rsqrtf(mv4.z + 1e-3f);
        const float bs3 = g4.w * rsqrtf(mv4.w + 1e-3f);
#pragma unroll
        for (int k = 0; k < 2; ++k) {
            const int j = k * 512 + tid;
            const int hl = j >> 5, wl = j & 31;
            float4 bx;
            // scale 2: rows hl+7..hl+8, cols wl+7..wl+8
            BOX(7, 2, bx);
            float ax = -0.3f * LG(bx.x);
            float ay = -0.3f * LG(bx.y);
            float az = -0.3f * LG(bx.z);
            float aw = -0.3f * LG(bx.w);
            // scale 4: rows hl+6..hl+9
            BOX(6, 4, bx);
            ax -= 0.1f * LG(bx.x);
            ay -= 0.1f * LG(bx.y);
            az -= 0.1f * LG(bx.z);
            aw -= 0.1f * LG(bx.w);
            // scale 8: rows hl+4..hl+11
            BOX(4, 8, bx);
            ax += 0.1f * LG(bx.x);
            ay += 0.1f * LG(bx.y);
            az += 0.1f * LG(bx.z);
            aw += 0.1f * LG(bx.w);
            // scale 16: rows hl..hl+15
            BOX(0, 16, bx);
            ax += 0.3f * LG(bx.x);
            ay += 0.3f * LG(bx.y);
            az += 0.3f * LG(bx.z);
            aw += 0.3f * LG(bx.w);

            float4 o4;
            o4.x = (ax - mm4.x) * bs0 + be4.x;
            o4.y = (ay - mm4.y) * bs1 + be4.y;
            o4.z = (az - mm4.z) * bs2 + be4.z;
            o4.w = (aw - mm4.w) * bs3 + be4.w;
            *(float4*)(ob + ((size_t)((th0 + hl) * W_ + (tw0 + wl))) * C_ + ch0) = o4;
        }
    }
}

extern "C" void kernel_launch(void* const* d_in, const int* in_sizes, int n_in,
                              void* d_out, int out_size, void* d_ws, size_t ws_size,
                              hipStream_t stream) {
    const float* x     = (const float*)d_in[0];
    const float* gamma = (const float*)d_in[1];
    const float* beta  = (const float*)d_in[2];
    const float* mmean = (const float*)d_in[3];
    const float* mvar  = (const float*)d_in[4];
    float* out = (float*)d_out;
    unsigned int* ws = (unsigned int*)d_ws;

    hipLaunchKernelGGL(init_ws, dim3(1), dim3(64), 0, stream, ws);
    hipLaunchKernelGGL(minmax_kernel, dim3(16, 64), dim3(256), 0, stream, x, ws);
    hipLaunchKernelGGL(lss_kernel, dim3(98 * 16), dim3(512), 0, stream,
                       x, gamma, beta, mmean, mvar, ws, out);
}